// Round 7
// baseline (296.218 us; speedup 1.0000x reference)
//
#include <hip/hip_runtime.h>
#include <hip/hip_bf16.h>

// RoIAlign (avg, aligned=True).
//   input: (4, 256, 200, 200) fp32, rois: (1024, 5) fp32
//   pooled 7x7, sampling_ratio=2, spatial_scale=0.25
//   out: (1024, 256, 7, 7) fp32
//
// R4 (resubmitted R5–R10 after seven infra failures — never yet measured):
// R3 (grouped-bf16 two-pass + ROI counting-sort + XCD swizzle) plus:
//   - branchless valid-masking in the gather: folds the torchvision `valid`
//     predicate into the bilinear weights so the 16 tap loads sit in ONE
//     basic block -> compiler can hoist/pipeline all 16 loads (MLP 16 vs 4).
//   - nontemporal stores for the 51 MB output (protect XCD-L2 gather set)
//     and nontemporal loads for the read-once 164 MB input in pass 1
//     (protect L3 residency of gfeat between pass 1 and pass 2).
//   - ROI counting-sort fused into block 0 of to_grouped (one fewer launch).

#define CCH 256
#define FH 200
#define FW 200
#define N_ROIS 1024
#define PP 49          // 7*7 bins
#define NG 8           // channel groups (256/32)
#define GSZ 32         // channels per group
#define PLANE (FH*FW)

// ---------- pass 1: NCHW fp32 -> grouped bf16 (+ fused ROI sort in blk 0) ----------
__global__ __launch_bounds__(256) void to_grouped(
    const float* __restrict__ in, unsigned short* __restrict__ gout,
    const float* __restrict__ rois, int* __restrict__ perm)
{
    if (blockIdx.x == 0) {
        // counting-sort 1024 ROIs by image index with 256 threads (4 each).
        // Any within-bucket order is valid: perm only reorders processing.
        __shared__ int cnt[4];
        __shared__ int base[4];
        int t = threadIdx.x;
        if (t < 4) cnt[t] = 0;
        __syncthreads();
        int bb[4], po[4];
        #pragma unroll
        for (int r = 0; r < 4; ++r) {
            int ri = r * 256 + t;
            int b = (int)rois[ri * 5];
            bb[r] = b;
            po[r] = atomicAdd(&cnt[b], 1);
        }
        __syncthreads();
        if (t == 0) {
            int s = 0;
            #pragma unroll
            for (int i = 0; i < 4; ++i) { base[i] = s; s += cnt[i]; }
        }
        __syncthreads();
        #pragma unroll
        for (int r = 0; r < 4; ++r)
            perm[base[bb[r]] + po[r]] = r * 256 + t;
    }

    int idx = blockIdx.x * 256 + threadIdx.x;   // 4*8*40000 = 1,280,000 exact
    int p  = idx % PLANE;
    int bg = idx / PLANE;                       // b*8+g ; c_base = 32*bg
    const float* src = in + (size_t)bg * GSZ * PLANE + p;

    unsigned short tmp[GSZ];
    #pragma unroll
    for (int j = 0; j < GSZ; ++j) {
        float f = __builtin_nontemporal_load(&src[(size_t)j * PLANE]);
        unsigned u = __float_as_uint(f);
        tmp[j] = (unsigned short)((u + 0x7FFFu + ((u >> 16) & 1u)) >> 16); // RNE
    }
    uint4* dst = (uint4*)(gout + (size_t)idx * GSZ);
    #pragma unroll
    for (int k = 0; k < 4; ++k) {
        uint4 q;
        __builtin_memcpy(&q, &tmp[k * 8], 16);
        dst[k] = q;
    }
}

// ---------- pass 2: gather ----------
__device__ __forceinline__ void fma8q(float* acc, uint4 q, float w)
{
    unsigned short u[8];
    __builtin_memcpy(u, &q, 16);
    #pragma unroll
    for (int j = 0; j < 8; ++j)
        acc[j] = fmaf(w, __uint_as_float((unsigned)u[j] << 16), acc[j]);
}

__global__ __launch_bounds__(256) void roi_align_grouped(
    const unsigned short* __restrict__ gfeat,
    const float* __restrict__ rois,
    const int* __restrict__ perm,
    float* __restrict__ out)
{
    // XCD swizzle: 6272 blocks / 8 XCDs = 784-block chunks; one g per XCD.
    int nb  = gridDim.x;                         // 6272, divisible by 8
    int vb  = (blockIdx.x & 7) * (nb >> 3) + (blockIdx.x >> 3);
    int idx = vb * 256 + threadIdx.x;            // 8*1024*49*4 exact

    int s      = idx & 3;                        // 8-channel slice
    int bin    = (idx >> 2) % PP;
    int n_slot = (idx / (4 * PP)) % N_ROIS;      // sorted position
    int g      = idx / (4 * PP * N_ROIS);
    int n      = perm[n_slot];                   // original ROI id
    int ph = bin / 7, pw = bin % 7;

    const float* roi = rois + n * 5;
    int   b  = (int)roi[0];
    float x1 = roi[1] * 0.25f - 0.5f;
    float y1 = roi[2] * 0.25f - 0.5f;
    float x2 = roi[3] * 0.25f - 0.5f;
    float y2 = roi[4] * 0.25f - 0.5f;
    float bin_h = (y2 - y1) / 7.0f;
    float bin_w = (x2 - x1) / 7.0f;

    const unsigned short* plane =
        gfeat + (size_t)(b * NG + g) * (size_t)PLANE * GSZ + s * 8;

    // Branchless per-axis samples: torchvision's `valid` predicate folds
    // into the weights (invalid sample -> weight 0; clamped index always
    // in-bounds so the load itself is safe). One basic block -> all 16
    // gather loads hoistable.
    int   yy0[2], yy1[2];
    float wy0[2], wy1[2];
    #pragma unroll
    for (int iy = 0; iy < 2; ++iy) {
        float y = y1 + ((float)ph + ((float)iy + 0.5f) * 0.5f) * bin_h;
        float v = (y >= -1.0f && y <= (float)FH) ? 1.0f : 0.0f;
        float yc = fminf(fmaxf(y, 0.0f), (float)(FH - 1));
        int   y0 = (int)yc;
        yy0[iy] = y0;
        yy1[iy] = min(y0 + 1, FH - 1);
        float ly = yc - (float)y0;
        wy1[iy] = ly * v;
        wy0[iy] = (1.0f - ly) * v;
    }
    int   xx0[2], xx1[2];
    float wx0[2], wx1[2];
    #pragma unroll
    for (int ix = 0; ix < 2; ++ix) {
        float x = x1 + ((float)pw + ((float)ix + 0.5f) * 0.5f) * bin_w;
        float v = (x >= -1.0f && x <= (float)FW) ? 1.0f : 0.0f;
        float xc = fminf(fmaxf(x, 0.0f), (float)(FW - 1));
        int   x0 = (int)xc;
        xx0[ix] = x0;
        xx1[ix] = min(x0 + 1, FW - 1);
        float lx = xc - (float)x0;
        wx1[ix] = lx * v;
        wx0[ix] = (1.0f - lx) * v;
    }

    float acc[8] = {0, 0, 0, 0, 0, 0, 0, 0};

    #pragma unroll
    for (int iy = 0; iy < 2; ++iy) {
        const unsigned short* r0 = plane + (size_t)(yy0[iy] * FW) * GSZ;
        const unsigned short* r1 = plane + (size_t)(yy1[iy] * FW) * GSZ;
        #pragma unroll
        for (int ix = 0; ix < 2; ++ix) {
            uint4 qA = *(const uint4*)(r0 + (size_t)xx0[ix] * GSZ);
            uint4 qB = *(const uint4*)(r0 + (size_t)xx1[ix] * GSZ);
            uint4 qC = *(const uint4*)(r1 + (size_t)xx0[ix] * GSZ);
            uint4 qD = *(const uint4*)(r1 + (size_t)xx1[ix] * GSZ);
            fma8q(acc, qA, wy0[iy] * wx0[ix]);
            fma8q(acc, qB, wy0[iy] * wx1[ix]);
            fma8q(acc, qC, wy1[iy] * wx0[ix]);
            fma8q(acc, qD, wy1[iy] * wx1[ix]);
        }
    }

    // out[n][c][bin], c = g*32 + s*8 + j  — streaming, keep out of L2.
    float* o = out + ((size_t)n * CCH + g * GSZ + s * 8) * PP + bin;
    #pragma unroll
    for (int j = 0; j < 8; ++j)
        __builtin_nontemporal_store(acc[j] * 0.25f, o + j * PP);
}

// ---------- fallback (R1 kernel) if ws too small ----------
__global__ __launch_bounds__(256) void roi_align_fallback(
    const float* __restrict__ feat, const float* __restrict__ rois,
    float* __restrict__ out, int total)
{
    int nb  = gridDim.x;
    int vid = (blockIdx.x & 7) * (nb >> 3) + (blockIdx.x >> 3);
    int idx = vid * 256 + threadIdx.x;
    if (idx >= total) return;
    int pw = idx % 7;
    int ph = (idx / 7) % 7;
    int n  = (idx / 49) & (N_ROIS - 1);
    int c  = idx / (49 * N_ROIS);

    const float* roi = rois + n * 5;
    int   b  = (int)roi[0];
    float x1 = roi[1] * 0.25f - 0.5f;
    float y1 = roi[2] * 0.25f - 0.5f;
    float x2 = roi[3] * 0.25f - 0.5f;
    float y2 = roi[4] * 0.25f - 0.5f;
    float bin_h = (y2 - y1) / 7.0f;
    float bin_w = (x2 - x1) / 7.0f;
    const float* plane = feat + ((size_t)b * CCH + c) * PLANE;

    float acc = 0.0f;
    #pragma unroll
    for (int iy = 0; iy < 2; ++iy) {
        float y = y1 + ((float)ph + ((float)iy + 0.5f) * 0.5f) * bin_h;
        if (y < -1.0f || y > (float)FH) continue;
        float yc = fminf(fmaxf(y, 0.0f), (float)(FH - 1));
        int y0 = (int)yc, y1i = min(y0 + 1, FH - 1);
        float ly = yc - (float)y0, hy = 1.0f - ly;
        #pragma unroll
        for (int ix = 0; ix < 2; ++ix) {
            float x = x1 + ((float)pw + ((float)ix + 0.5f) * 0.5f) * bin_w;
            if (x < -1.0f || x > (float)FW) continue;
            float xc = fminf(fmaxf(x, 0.0f), (float)(FW - 1));
            int x0 = (int)xc, x1i = min(x0 + 1, FW - 1);
            float lx = xc - (float)x0, hx = 1.0f - lx;
            acc += hy * (hx * plane[y0 * FW + x0] + lx * plane[y0 * FW + x1i])
                 + ly * (hx * plane[y1i * FW + x0] + lx * plane[y1i * FW + x1i]);
        }
    }
    out[((size_t)n * CCH + c) * PP + ph * 7 + pw] = acc * 0.25f;
}

extern "C" void kernel_launch(void* const* d_in, const int* in_sizes, int n_in,
                              void* d_out, int out_size, void* d_ws, size_t ws_size,
                              hipStream_t stream)
{
    const float* feat = (const float*)d_in[0];
    const float* rois = (const float*)d_in[1];
    float* out = (float*)d_out;

    const size_t gfeat_bytes = (size_t)4 * NG * PLANE * GSZ * 2;  // 81.92 MB
    const size_t ws_needed = gfeat_bytes + N_ROIS * sizeof(int);

    if (ws_size >= ws_needed) {
        unsigned short* gfeat = (unsigned short*)d_ws;
        int* perm = (int*)((char*)d_ws + gfeat_bytes);
        to_grouped<<<(4 * NG * PLANE) / 256, 256, 0, stream>>>(feat, gfeat, rois, perm);
        int items = NG * N_ROIS * PP * 4;            // 1,605,632
        roi_align_grouped<<<items / 256, 256, 0, stream>>>(gfeat, rois, perm, out);
    } else {
        int total = out_size;
        int grid = (total + 255) / 256;
        roi_align_fallback<<<grid, 256, 0, stream>>>(feat, rois, out, total);
    }
}